// Round 3
// baseline (73.799 us; speedup 1.0000x reference)
//
#include <hip/hip_runtime.h>
#include <math.h>

typedef __attribute__((ext_vector_type(8))) short short8;
typedef __attribute__((ext_vector_type(4))) float f32x4;
typedef unsigned short ushort_t;

#define B_ 4
#define N_ 4096
#define E_ 256
#define D_ 64
#define S2LOG 0.1803368801f   // (1/sqrt(64)) * log2(e)  -> softmax in log2 domain
#define BIGNEG (-1e30f)
#define THR 8.0f              // defer-max threshold (log2 units)

static __device__ __forceinline__ unsigned short f2bf(float f) {
  union { float f; unsigned int u; } v; v.f = f;
  return (unsigned short)((v.u + 0x7fffu + ((v.u >> 16) & 1u)) >> 16);  // RNE
}
static __device__ __forceinline__ float exp2_fast(float x) {
  float r; asm("v_exp_f32 %0, %1" : "=v"(r) : "v"(x)); return r;
}
static __device__ __forceinline__ unsigned cvt_pk_bf16(float lo, float hi) {
  unsigned r; asm("v_cvt_pk_bf16_f32 %0, %1, %2" : "=v"(r) : "v"(lo), "v"(hi));
  return r;
}

// ---------------------------------------------------------------------------
// Projection: out = X @ W^T  (X:[B*N,256] f32, W:[64,256] f32) -> bf16
// p=0: q [B*N][64] (+ mask->bias fold); p=1: k [B*N][64]; p=2: vT [B][64][N]
// ---------------------------------------------------------------------------
__global__ __launch_bounds__(256) void proj_kernel(
    const float* __restrict__ Qv, const float* __restrict__ Kv,
    const float* __restrict__ Vv, const float* __restrict__ Wq,
    const float* __restrict__ Wk, const float* __restrict__ Wv,
    const int* __restrict__ mask,
    unsigned short* __restrict__ qo, unsigned short* __restrict__ ko,
    unsigned short* __restrict__ vto, float* __restrict__ biasf)
{
  const int p  = blockIdx.y;
  const int rb = blockIdx.x;
  const int t  = threadIdx.x;

  __align__(16) __shared__ unsigned short Xl[64 * 264];
  __align__(16) __shared__ unsigned short Wl[64 * 264];

  const float* xsrc = (p == 0 ? Qv : (p == 1 ? Kv : Vv)) + (size_t)rb * 64 * E_;
  const float* wsrc = (p == 0 ? Wq : (p == 1 ? Wk : Wv));

  if (p == 0 && t < 64) biasf[rb * 64 + t] = mask[rb * 64 + t] ? 0.f : BIGNEG;

  #pragma unroll
  for (int it = 0; it < 8; ++it) {
    int idx = it * 2048 + t * 8;
    int row = idx >> 8, col = idx & 255;
    float4 a0 = *(const float4*)(xsrc + idx);
    float4 a1 = *(const float4*)(xsrc + idx + 4);
    uint4 wx;
    wx.x = (unsigned)f2bf(a0.x) | ((unsigned)f2bf(a0.y) << 16);
    wx.y = (unsigned)f2bf(a0.z) | ((unsigned)f2bf(a0.w) << 16);
    wx.z = (unsigned)f2bf(a1.x) | ((unsigned)f2bf(a1.y) << 16);
    wx.w = (unsigned)f2bf(a1.z) | ((unsigned)f2bf(a1.w) << 16);
    *(uint4*)&Xl[row * 264 + col] = wx;
    float4 b0 = *(const float4*)(wsrc + idx);
    float4 b1 = *(const float4*)(wsrc + idx + 4);
    uint4 ww;
    ww.x = (unsigned)f2bf(b0.x) | ((unsigned)f2bf(b0.y) << 16);
    ww.y = (unsigned)f2bf(b0.z) | ((unsigned)f2bf(b0.w) << 16);
    ww.z = (unsigned)f2bf(b1.x) | ((unsigned)f2bf(b1.y) << 16);
    ww.w = (unsigned)f2bf(b1.z) | ((unsigned)f2bf(b1.w) << 16);
    *(uint4*)&Wl[row * 264 + col] = ww;
  }
  __syncthreads();

  const int wave = t >> 6, lane = t & 63, g = lane >> 4, lq = lane & 15;
  const unsigned short* TA = (p == 2) ? Wl : Xl;
  const unsigned short* TB = (p == 2) ? Xl : Wl;

  f32x4 acc0 = {0.f,0.f,0.f,0.f}, acc1 = acc0, acc2 = acc0, acc3 = acc0;
  #pragma unroll
  for (int kc = 0; kc < 8; ++kc) {
    short8 af = *(const short8*)&TA[(wave * 16 + lq) * 264 + kc * 32 + g * 8];
    short8 b0 = *(const short8*)&TB[(0 * 16 + lq) * 264 + kc * 32 + g * 8];
    acc0 = __builtin_amdgcn_mfma_f32_16x16x32_bf16(af, b0, acc0, 0, 0, 0);
    short8 b1 = *(const short8*)&TB[(1 * 16 + lq) * 264 + kc * 32 + g * 8];
    acc1 = __builtin_amdgcn_mfma_f32_16x16x32_bf16(af, b1, acc1, 0, 0, 0);
    short8 b2 = *(const short8*)&TB[(2 * 16 + lq) * 264 + kc * 32 + g * 8];
    acc2 = __builtin_amdgcn_mfma_f32_16x16x32_bf16(af, b2, acc2, 0, 0, 0);
    short8 b3 = *(const short8*)&TB[(3 * 16 + lq) * 264 + kc * 32 + g * 8];
    acc3 = __builtin_amdgcn_mfma_f32_16x16x32_bf16(af, b3, acc3, 0, 0, 0);
  }

  if (p < 2) {
    unsigned short* dst = (p == 0 ? qo : ko);
    #pragma unroll
    for (int c = 0; c < 4; ++c) {
      const f32x4 ac = (c == 0 ? acc0 : c == 1 ? acc1 : c == 2 ? acc2 : acc3);
      #pragma unroll
      for (int r = 0; r < 4; ++r) {
        int n = rb * 64 + wave * 16 + g * 4 + r;
        dst[(size_t)n * D_ + c * 16 + lq] = f2bf(ac[r]);
      }
    }
  } else {
    int bb = (rb * 64) >> 12;
    #pragma unroll
    for (int c = 0; c < 4; ++c) {
      const f32x4 ac = (c == 0 ? acc0 : c == 1 ? acc1 : c == 2 ? acc2 : acc3);
      #pragma unroll
      for (int r = 0; r < 4; ++r) {
        int d = wave * 16 + g * 4 + r;
        int n = (rb * 64 + c * 16 + lq) & (N_ - 1);
        vto[((size_t)bb * D_ + d) * N_ + n] = f2bf(ac[r]);
      }
    }
  }
}

// ---------------------------------------------------------------------------
// vmean[b][d] = (1/N) sum_n v[b][n][d]   (dead-q-row reference semantics)
// ---------------------------------------------------------------------------
__global__ __launch_bounds__(256) void vmean_kernel(
    const ushort_t* __restrict__ vt, float* __restrict__ vmean)
{
  const int b = blockIdx.x, t = threadIdx.x;
  const int d = t >> 2, part = t & 3;
  const ushort_t* row = vt + ((size_t)b * D_ + d) * N_ + part * (N_ / 4);
  float s = 0.f;
  for (int i = 0; i < N_ / 4; i += 8) {
    short8 v = *(const short8*)&row[i];
    #pragma unroll
    for (int j = 0; j < 8; ++j) {
      union { unsigned u; float f; } c; c.u = ((unsigned)(unsigned short)v[j]) << 16;
      s += c.f;
    }
  }
  s += __shfl_xor(s, 1, 64);
  s += __shfl_xor(s, 2, 64);
  if (part == 0) vmean[b * D_ + d] = s * (1.f / N_);
}

// ---------------------------------------------------------------------------
// Flash attention, KV-split, log2-domain online softmax with defer-max.
// Block = 4 waves x 16 q-rows; key tile 64; double-buffered swizzled LDS.
// LDS = 40960 B exactly -> 4 blocks/CU.
// ---------------------------------------------------------------------------
__global__ __launch_bounds__(256, 4) void attn3_kernel(
    const ushort_t* __restrict__ q, const ushort_t* __restrict__ kk,
    const ushort_t* __restrict__ vt, const float* __restrict__ biasf,
    float* __restrict__ op0, float* __restrict__ opws,
    float* __restrict__ mlbuf, int nsplit)
{
  const int b = blockIdx.y, qt = blockIdx.x, sp = blockIdx.z;
  const int t = threadIdx.x;
  const int wave = t >> 6, lane = t & 63, g = lane >> 4, lq = lane & 15;

  const int TT = N_ / 64;
  const int tile_lo = (sp * TT) / nsplit;
  const int tile_hi = ((sp + 1) * TT) / nsplit;
  const int nit = tile_hi - tile_lo;

  __align__(16) __shared__ ushort_t Kt[2][64 * 64];   // [key][d], 16B-chunk XOR swz
  __align__(16) __shared__ ushort_t Vt[2][64 * 64];   // [d][key], 16B-chunk XOR swz
  __align__(16) __shared__ ushort_t Pl[4][16 * 64];   // per-wave P, XOR swz

  const int qrow_b = qt * 64 + wave * 16 + lq;
  const size_t qoff = (size_t)(b * N_ + qrow_b) * D_;
  short8 qf0 = *(const short8*)&q[qoff + g * 8];
  short8 qf1 = *(const short8*)&q[qoff + 32 + g * 8];
  const float* biasb = biasf + b * N_;

  float m = -INFINITY, lsum = 0.f;
  f32x4 o[4];
  #pragma unroll
  for (int i = 0; i < 4; ++i) o[i] = f32x4{0.f, 0.f, 0.f, 0.f};

  const int r0 = t >> 3, j0 = t & 7;
  const int r1 = 32 + (t >> 3);

  uint4 k0, k1, v0, v1;

  auto stage_load = [&](int tile) {
    const int jb = (tile_lo + tile) * 64;
    const ushort_t* kbase = kk + (size_t)(b * N_ + jb) * D_;
    k0 = *(const uint4*)&kbase[(size_t)r0 * D_ + j0 * 8];
    k1 = *(const uint4*)&kbase[(size_t)r1 * D_ + j0 * 8];
    const ushort_t* vbase = vt + (size_t)b * D_ * N_ + jb;
    v0 = *(const uint4*)&vbase[(size_t)r0 * N_ + j0 * 8];
    v1 = *(const uint4*)&vbase[(size_t)r1 * N_ + j0 * 8];
  };
  auto stage_write = [&](int bufi) {
    *(uint4*)&Kt[bufi][r0 * 64 + ((j0 ^ (r0 & 7)) * 8)] = k0;
    *(uint4*)&Kt[bufi][r1 * 64 + ((j0 ^ (r1 & 7)) * 8)] = k1;
    *(uint4*)&Vt[bufi][r0 * 64 + ((j0 ^ (r0 & 7)) * 8)] = v0;
    *(uint4*)&Vt[bufi][r1 * 64 + ((j0 ^ (r1 & 7)) * 8)] = v1;
  };

  stage_load(0);
  stage_write(0);
  __syncthreads();

  for (int it = 0; it < nit; ++it) {
    const int bufi = it & 1;
    const int jb = (tile_lo + it) * 64;
    const bool more = (it + 1 < nit);
    if (more) stage_load(it + 1);      // VMEM in flight across compute

    // bias for this tile's 16 keys/lane (L1-hot 16 KB array, broadcast)
    float4 bf0 = *(const float4*)&biasb[jb + 0 * 16 + 4 * g];
    float4 bf1 = *(const float4*)&biasb[jb + 1 * 16 + 4 * g];
    float4 bf2 = *(const float4*)&biasb[jb + 2 * 16 + 4 * g];
    float4 bf3 = *(const float4*)&biasb[jb + 3 * 16 + 4 * g];

    // ---- QK^T (swapped: C rows = keys, cols = q) ----
    f32x4 st[4];
    #pragma unroll
    for (int kc = 0; kc < 4; ++kc) st[kc] = f32x4{0.f, 0.f, 0.f, 0.f};
    __builtin_amdgcn_s_setprio(1);
    #pragma unroll
    for (int kc = 0; kc < 4; ++kc) {
      const int row = kc * 16 + lq, sw = row & 7;
      short8 a0 = *(const short8*)&Kt[bufi][row * 64 + ((g ^ sw) * 8)];
      st[kc] = __builtin_amdgcn_mfma_f32_16x16x32_bf16(a0, qf0, st[kc], 0, 0, 0);
      short8 a1 = *(const short8*)&Kt[bufi][row * 64 + (((4 + g) ^ sw) * 8)];
      st[kc] = __builtin_amdgcn_mfma_f32_16x16x32_bf16(a1, qf1, st[kc], 0, 0, 0);
    }
    __builtin_amdgcn_s_setprio(0);

    // ---- scores in log2 domain ----
    float sv[16];
    #pragma unroll
    for (int kc = 0; kc < 4; ++kc) {
      const float4 bf = (kc == 0 ? bf0 : kc == 1 ? bf1 : kc == 2 ? bf2 : bf3);
      sv[kc * 4 + 0] = fmaf(st[kc][0], S2LOG, bf.x);
      sv[kc * 4 + 1] = fmaf(st[kc][1], S2LOG, bf.y);
      sv[kc * 4 + 2] = fmaf(st[kc][2], S2LOG, bf.z);
      sv[kc * 4 + 3] = fmaf(st[kc][3], S2LOG, bf.w);
    }
    if (jb == qt * 64) {               // diagonal tile only (uniform branch)
      const int dref = qrow_b - jb - 4 * g;   // klocal-4g = 16kc+r must equal dref
      #pragma unroll
      for (int kc = 0; kc < 4; ++kc)
        #pragma unroll
        for (int r = 0; r < 4; ++r)
          sv[kc * 4 + r] = (16 * kc + r == dref) ? BIGNEG : sv[kc * 4 + r];
    }

    // ---- row max (max3 tree + cross-lane) ----
    float a0m = fmaxf(fmaxf(sv[0], sv[1]), sv[2]);
    float a1m = fmaxf(fmaxf(sv[3], sv[4]), sv[5]);
    float a2m = fmaxf(fmaxf(sv[6], sv[7]), sv[8]);
    float a3m = fmaxf(fmaxf(sv[9], sv[10]), sv[11]);
    float a4m = fmaxf(fmaxf(sv[12], sv[13]), sv[14]);
    float b0m = fmaxf(fmaxf(a0m, a1m), a2m);
    float b1m = fmaxf(fmaxf(a3m, a4m), sv[15]);
    float tm = fmaxf(b0m, b1m);
    tm = fmaxf(tm, __shfl_xor(tm, 16, 64));
    tm = fmaxf(tm, __shfl_xor(tm, 32, 64));

    // ---- defer-max: rescale only when the max moved by > THR ----
    if (!__all(tm - m <= THR)) {
      const float mnew = fmaxf(m, tm);
      const float corr = exp2_fast(m - mnew);
      const float c0 = __shfl(corr, g * 4 + 0, 64);
      const float c1 = __shfl(corr, g * 4 + 1, 64);
      const float c2 = __shfl(corr, g * 4 + 2, 64);
      const float c3 = __shfl(corr, g * 4 + 3, 64);
      #pragma unroll
      for (int dc = 0; dc < 4; ++dc) {
        o[dc][0] *= c0; o[dc][1] *= c1; o[dc][2] *= c2; o[dc][3] *= c3;
      }
      lsum *= corr;
      m = mnew;
    }

    // ---- P = exp2(sv - m), pack bf16, partial row-sum ----
    float p[16];
    #pragma unroll
    for (int i = 0; i < 16; ++i) p[i] = exp2_fast(sv[i] - m);
    unsigned pw[8];
    #pragma unroll
    for (int h = 0; h < 8; ++h) pw[h] = cvt_pk_bf16(p[2 * h], p[2 * h + 1]);
    float ps = ((p[0] + p[1]) + (p[2] + p[3])) + ((p[4] + p[5]) + (p[6] + p[7]))
             + ((p[8] + p[9]) + (p[10] + p[11])) + ((p[12] + p[13]) + (p[14] + p[15]));
    ps += __shfl_xor(ps, 16, 64);
    ps += __shfl_xor(ps, 32, 64);
    lsum += ps;

    // ---- P bounce to per-wave swizzled LDS ----
    #pragma unroll
    for (int kc = 0; kc < 4; ++kc) {
      uint2 w; w.x = pw[kc * 2]; w.y = pw[kc * 2 + 1];
      const int c16 = 2 * kc + (g >> 1);
      *(uint2*)&Pl[wave][lq * 64 + ((c16 ^ (lq & 7)) << 3) + ((g & 1) << 2)] = w;
    }
    asm volatile("s_waitcnt lgkmcnt(0)" ::: "memory");
    __builtin_amdgcn_sched_barrier(0);

    // ---- PV ----
    short8 pf0 = *(const short8*)&Pl[wave][lq * 64 + ((g ^ (lq & 7)) << 3)];
    short8 pf1 = *(const short8*)&Pl[wave][lq * 64 + (((4 + g) ^ (lq & 7)) << 3)];
    __builtin_amdgcn_s_setprio(1);
    #pragma unroll
    for (int dc = 0; dc < 4; ++dc) {
      const int row = dc * 16 + lq, sw = row & 7;
      short8 vv0 = *(const short8*)&Vt[bufi][row * 64 + ((g ^ sw) * 8)];
      o[dc] = __builtin_amdgcn_mfma_f32_16x16x32_bf16(pf0, vv0, o[dc], 0, 0, 0);
      short8 vv1 = *(const short8*)&Vt[bufi][row * 64 + (((4 + g) ^ sw) * 8)];
      o[dc] = __builtin_amdgcn_mfma_f32_16x16x32_bf16(pf1, vv1, o[dc], 0, 0, 0);
    }
    __builtin_amdgcn_s_setprio(0);

    if (more) stage_write(bufi ^ 1);
    __syncthreads();
  }

  // ---- epilogue: unnormalized O' + (m,l) ----
  float* obase = (sp == 0 ? op0 : opws + (size_t)(sp - 1) * (B_ * N_) * D_)
               + ((size_t)(b * N_) + qt * 64 + wave * 16) * D_;
  #pragma unroll
  for (int dc = 0; dc < 4; ++dc) {
    #pragma unroll
    for (int r = 0; r < 4; ++r)
      obase[(size_t)(g * 4 + r) * D_ + dc * 16 + lq] = o[dc][r];
  }
  if (g == 0) {
    float* mlp = mlbuf + ((size_t)sp * (B_ * N_) + b * N_ + qt * 64 + wave * 16 + lq) * 2;
    mlp[0] = m; mlp[1] = lsum;
  }
}

// ---------------------------------------------------------------------------
// Merge splits; dead q-rows get the reference's uniform mean over all V.
// ---------------------------------------------------------------------------
__global__ __launch_bounds__(256) void merge_kernel(
    const float* __restrict__ op0, const float* __restrict__ opws,
    const float* __restrict__ mlbuf, const int* __restrict__ mask,
    const float* __restrict__ vmean, float* __restrict__ out, int nsplit)
{
  const int t = threadIdx.x;
  const int qrow = blockIdx.x * 16 + (t >> 4);
  const int d = (t & 15) * 4;
  const int b = qrow >> 12;

  if (!mask[qrow]) {
    *(float4*)&out[(size_t)qrow * D_ + d] = *(const float4*)&vmean[b * D_ + d];
    return;
  }

  float M = -INFINITY;
  for (int s = 0; s < nsplit; ++s)
    M = fmaxf(M, mlbuf[((size_t)s * (B_ * N_) + qrow) * 2]);

  float L = 0.f;
  float ax = 0.f, ay = 0.f, az = 0.f, aw = 0.f;
  for (int s = 0; s < nsplit; ++s) {
    const float* mlp = &mlbuf[((size_t)s * (B_ * N_) + qrow) * 2];
    const float w = exp2_fast(mlp[0] - M);
    L += mlp[1] * w;
    const float* ob = (s == 0) ? op0 : opws + (size_t)(s - 1) * (B_ * N_) * D_;
    float4 ov = *(const float4*)&ob[(size_t)qrow * D_ + d];
    ax += ov.x * w; ay += ov.y * w; az += ov.z * w; aw += ov.w * w;
  }
  const float inv = 1.f / L;
  float4 res; res.x = ax * inv; res.y = ay * inv; res.z = az * inv; res.w = aw * inv;
  *(float4*)&out[(size_t)qrow * D_ + d] = res;
}

// ---------------------------------------------------------------------------
extern "C" void kernel_launch(void* const* d_in, const int* in_sizes, int n_in,
                              void* d_out, int out_size, void* d_ws, size_t ws_size,
                              hipStream_t stream) {
  (void)in_sizes; (void)n_in; (void)out_size;
  const float* Qv = (const float*)d_in[0];
  const float* Kv = (const float*)d_in[1];
  const float* Vv = (const float*)d_in[2];
  const int* mask = (const int*)d_in[3];
  const float* Wq = (const float*)d_in[4];
  const float* Wk = (const float*)d_in[5];
  const float* Wv = (const float*)d_in[6];
  float* out = (float*)d_out;

  ushort_t* qb_ = (ushort_t*)d_ws;                         // [B*N][64] bf16
  ushort_t* kb_ = qb_ + (size_t)B_ * N_ * D_;              // [B*N][64] bf16
  ushort_t* vtb = kb_ + (size_t)B_ * N_ * D_;              // [B][64][N] bf16
  float* biasf  = (float*)(vtb + (size_t)B_ * N_ * D_);    // [B*N] f32
  float* vmean  = biasf + (size_t)B_ * N_;                 // [B][64] f32
  float* mlbuf  = vmean + (size_t)B_ * D_;                 // [4][B*N][2] f32 max
  float* opws   = mlbuf + (size_t)4 * B_ * N_ * 2;         // (nsplit-1) x [B*N][64] f32
  const size_t fixed_bytes = (size_t)((char*)opws - (char*)d_ws);
  const size_t slice_bytes = (size_t)B_ * N_ * D_ * sizeof(float);

  int nsplit = 1;
  if      (ws_size >= fixed_bytes + 3 * slice_bytes) nsplit = 4;
  else if (ws_size >= fixed_bytes + 2 * slice_bytes) nsplit = 3;
  else if (ws_size >= fixed_bytes + 1 * slice_bytes) nsplit = 2;

  proj_kernel<<<dim3(256, 3), dim3(256), 0, stream>>>(
      Qv, Kv, Vv, Wq, Wk, Wv, mask, qb_, kb_, vtb, biasf);
  vmean_kernel<<<dim3(B_), dim3(256), 0, stream>>>(vtb, vmean);
  attn3_kernel<<<dim3(N_ / 64, B_, nsplit), dim3(256), 0, stream>>>(
      qb_, kb_, vtb, biasf, out, opws, mlbuf, nsplit);
  merge_kernel<<<dim3(B_ * N_ / 16), dim3(256), 0, stream>>>(
      out, opws, mlbuf, mask, vmean, out, nsplit);
}